// Round 1
// baseline (168.043 us; speedup 1.0000x reference)
//
#include <hip/hip_runtime.h>

#define SEG 24
#define DD  32
#define HEPS 1e-7f
#define N_ITERS 10

__device__ __forceinline__ float frcp(float x) { return __builtin_amdgcn_rcpf(x); }

// coef = arccosh(alpha)/sqrt(alpha^2 - 1), alpha >= 1 + 1e-7 guaranteed by caller
__device__ __forceinline__ float acosh_coef(float alpha) {
    float am = fmaf(alpha, alpha, -1.0f);   // >= ~2.4e-7 after the clamp
    float s  = sqrtf(am);
    return __logf(alpha + s) * frcp(s);
}

__global__ __launch_bounds__(256, 1)
void slmw_kernel(const float* __restrict__ x0, const float* __restrict__ x1,
                 const float* __restrict__ x2, const float* __restrict__ x3,
                 const float* __restrict__ W0, const float* __restrict__ b0,
                 const float* __restrict__ W1, const float* __restrict__ b1,
                 const float* __restrict__ W2, const float* __restrict__ b2,
                 const float* __restrict__ W3, const float* __restrict__ b3,
                 const float* __restrict__ es, const float* __restrict__ lw,
                 float* __restrict__ out, int n_items)
{
    const int item = blockIdx.x * blockDim.x + threadIdx.x;
    if (item >= n_items) return;

    const float ts = tanhf(es[0]);

    // softmax over the 4 lorentz weights (wave-uniform scalar math)
    float l0 = lw[0], l1 = lw[1], l2 = lw[2], l3 = lw[3];
    float mx = fmaxf(fmaxf(l0, l1), fmaxf(l2, l3));
    float e0 = __expf(l0 - mx), e1 = __expf(l1 - mx),
          e2 = __expf(l2 - mx), e3 = __expf(l3 - mx);
    float inv = frcp(e0 + e1 + e2 + e3);
    float w4[4] = { e0 * inv, e1 * inv, e2 * inv, e3 * inv };

    const float* xs[4] = { x0, x1, x2, x3 };
    const float* Ws[4] = { W0, W1, W2, W3 };
    const float* bs[4] = { b0, b1, b2, b3 };

    const size_t base = (size_t)item * SEG;
    const size_t osz  = (size_t)n_items * DD;

    float h[4][DD];

    // ---- encode + to_hyperbolic per stream; write h_s and keep in regs ----
    #pragma unroll
    for (int s = 0; s < 4; ++s) {
        const float4* sp = reinterpret_cast<const float4*>(xs[s] + base);
        float seg[SEG];
        #pragma unroll
        for (int j = 0; j < SEG / 4; ++j) {
            float4 v = sp[j];
            seg[4*j+0] = v.x; seg[4*j+1] = v.y; seg[4*j+2] = v.z; seg[4*j+3] = v.w;
        }
        float u[DD];
        #pragma unroll
        for (int d = 0; d < DD; ++d) {
            float z = bs[s][d];                      // wave-uniform -> s_load
            #pragma unroll
            for (int k = 0; k < SEG; ++k)
                z = fmaf(seg[k], Ws[s][d * SEG + k], z);   // SGPR operand FMA
            u[d] = z * ts;
        }
        // safe_expmap0 (space part only; time comp is overwritten by projx)
        float sq = -u[0] * u[0];
        #pragma unroll
        for (int d = 1; d < DD; ++d) sq = fmaf(u[d], u[d], sq);
        sq = fmaxf(sq, 1e-12f);
        float nrm = sqrtf(sq);
        float ep = __expf(nrm), em = __expf(-nrm);
        float sh = 0.5f * (ep - em);
        float sc = sh * frcp(fmaxf(nrm, HEPS));
        float ss = 0.0f;
        #pragma unroll
        for (int d = 1; d < DD; ++d) {
            float y = sc * u[d];
            h[s][d] = y;
            ss = fmaf(y, y, ss);
        }
        h[s][0] = sqrtf(1.0f + ss);                  // projx time component

        float* op = out + (size_t)s * osz + (size_t)item * DD;
        #pragma unroll
        for (int j = 0; j < DD / 4; ++j) {
            float4 v = { h[s][4*j+0], h[s][4*j+1], h[s][4*j+2], h[s][4*j+3] };
            reinterpret_cast<float4*>(op)[j] = v;
        }
    }

    // ---- fusion init: t0 = sum_s w_s * logmap0(h_s); mean = projx(expmap0(t0)) ----
    float mean[DD];
    {
        float t0[DD];
        #pragma unroll
        for (int d = 0; d < DD; ++d) t0[d] = 0.0f;
        #pragma unroll
        for (int s = 0; s < 4; ++s) {
            float y0    = h[s][0];
            float alpha = fmaxf(y0, 1.0f + HEPS);
            float c     = w4[s] * acosh_coef(alpha);
            t0[0] = fmaf(c, y0 - alpha, t0[0]);
            #pragma unroll
            for (int d = 1; d < DD; ++d) t0[d] = fmaf(c, h[s][d], t0[d]);
        }
        float sq = -t0[0] * t0[0];
        #pragma unroll
        for (int d = 1; d < DD; ++d) sq = fmaf(t0[d], t0[d], sq);
        sq = fmaxf(sq, 1e-12f);
        float nrm = sqrtf(sq);
        float ep = __expf(nrm), em = __expf(-nrm);
        float sh = 0.5f * (ep - em);
        float sc = sh * frcp(fmaxf(nrm, HEPS));
        float ss = 0.0f;
        #pragma unroll
        for (int d = 1; d < DD; ++d) {
            float y = sc * t0[d];
            mean[d] = y;
            ss = fmaf(y, y, ss);
        }
        mean[0] = sqrtf(1.0f + ss);
    }

    // ---- Frechet refinement, 10 iterations (global early-exit dropped:
    //      once max||wv|| < 1e-5 further updates move mean by < 5e-6/step) ----
    for (int it = 0; it < N_ITERS; ++it) {
        float wv[DD];
        #pragma unroll
        for (int d = 0; d < DD; ++d) wv[d] = 0.0f;
        #pragma unroll
        for (int s = 0; s < 4; ++s) {
            // alpha = -<mean, h_s>_L = m0*h0 - sum_{d>=1} m_d h_d
            float a = mean[0] * h[s][0];
            #pragma unroll
            for (int d = 1; d < DD; ++d) a = fmaf(-mean[d], h[s][d], a);
            float alpha = fmaxf(a, 1.0f + HEPS);
            float c = w4[s] * acosh_coef(alpha);
            #pragma unroll
            for (int d = 0; d < DD; ++d)
                wv[d] = fmaf(c, fmaf(-alpha, mean[d], h[s][d]), wv[d]);
        }
        // u = 0.5*wv ; mean = projx(cosh(n)*mean + sinh(n)*u/max(n,eps))
        float sq = -wv[0] * wv[0];
        #pragma unroll
        for (int d = 1; d < DD; ++d) sq = fmaf(wv[d], wv[d], sq);
        sq = fmaxf(0.25f * sq, 1e-12f);
        float nrm = sqrtf(sq);
        float ep = __expf(nrm), em = __expf(-nrm);
        float ch = 0.5f * (ep + em);
        float sh = 0.5f * (ep - em);
        float sc = 0.5f * sh * frcp(fmaxf(nrm, HEPS));
        float ss = 0.0f;
        #pragma unroll
        for (int d = 1; d < DD; ++d) {
            float y = fmaf(ch, mean[d], sc * wv[d]);
            mean[d] = y;
            ss = fmaf(y, y, ss);
        }
        mean[0] = sqrtf(1.0f + ss);
    }

    // ---- store combined mean ----
    float* op = out + (size_t)4 * osz + (size_t)item * DD;
    #pragma unroll
    for (int j = 0; j < DD / 4; ++j) {
        float4 v = { mean[4*j+0], mean[4*j+1], mean[4*j+2], mean[4*j+3] };
        reinterpret_cast<float4*>(op)[j] = v;
    }
}

extern "C" void kernel_launch(void* const* d_in, const int* in_sizes, int n_in,
                              void* d_out, int out_size, void* d_ws, size_t ws_size,
                              hipStream_t stream)
{
    const float* x0 = (const float*)d_in[0];
    const float* x1 = (const float*)d_in[1];
    const float* x2 = (const float*)d_in[2];
    const float* x3 = (const float*)d_in[3];
    const float* W0 = (const float*)d_in[4];
    const float* b0 = (const float*)d_in[5];
    const float* W1 = (const float*)d_in[6];
    const float* b1 = (const float*)d_in[7];
    const float* W2 = (const float*)d_in[8];
    const float* b2 = (const float*)d_in[9];
    const float* W3 = (const float*)d_in[10];
    const float* b3 = (const float*)d_in[11];
    const float* es = (const float*)d_in[12];
    const float* lw = (const float*)d_in[13];

    const int n_items = in_sizes[0] / SEG;   // 2048*3072/24 = 262144
    const int block = 256;
    const int grid  = (n_items + block - 1) / block;

    slmw_kernel<<<grid, block, 0, stream>>>(x0, x1, x2, x3,
                                            W0, b0, W1, b1, W2, b2, W3, b3,
                                            es, lw, (float*)d_out, n_items);
}